// Round 1
// baseline (800.203 us; speedup 1.0000x reference)
//
#include <hip/hip_runtime.h>
#include <math.h>

namespace {

constexpr int TT    = 32;    // T
constexpr int DD    = 158;   // D
constexpr int NEWSC = 1024;  // NEWS
constexpr int XDIM  = 1182;  // D + NEWS
constexpr int XPAD  = 1184;  // padded row stride (16B-aligned rows)
constexpr int DGRU  = 128;
constexpr int HIDN  = 64;    // G*E
constexpr int RPB   = 8;     // rows per block
constexpr int SPLIT = 592;   // router i-split (592 + 590), multiple of 8

__global__ __launch_bounds__(256, 2)
void miga_fused(const float* __restrict__ price,
                const float* __restrict__ news,
                const float* __restrict__ mask,
                const float* __restrict__ rW,
                const float* __restrict__ rb,
                const float* __restrict__ gW,
                const float* __restrict__ gb,
                const float* __restrict__ eW,
                const float* __restrict__ eb,
                const float* __restrict__ wq,
                const float* __restrict__ wqb,
                const float* __restrict__ wk,
                const float* __restrict__ wkb,
                const float* __restrict__ wv,
                const float* __restrict__ wvb,
                const float* __restrict__ wo,
                const float* __restrict__ wob,
                float* __restrict__ out, int nrows)
{
  // 58.4 KB static LDS total -> 2 blocks/CU (8 waves/CU)
  __shared__ __align__(16) float xs[RPB][XPAD];   // x = concat(price_agg, news_agg); reused for eWt later
  __shared__ float hs[RPB][DGRU];                 // h = tanh(x @ rW + rb)
  __shared__ float part[RPB][DGRU];               // router partial sums (half 1)
  __shared__ float hid_s[RPB][HIDN];
  __shared__ float eo_s[RPB][HIDN];
  __shared__ float q_s[RPB][HIDN];
  __shared__ float k_s[RPB][HIDN];
  __shared__ float v_s[RPB][HIDN];
  __shared__ float att_s[RPB][HIDN];
  __shared__ float den_m[RPB];                    // clip(mask.sum, 1e-6)

  // transposed expert_W [j][ge], stride 65 (bank-conflict-free), aliases dead xs
  float* eWt = &xs[0][0];

  const int tid  = threadIdx.x;
  const int row0 = blockIdx.x * RPB;

  // ---- mask sums (denominator for news aggregation) ----
  if (tid < RPB) {
    float s = 0.f;
    #pragma unroll
    for (int t = 0; t < TT; ++t) s += mask[(size_t)(row0 + tid) * TT + t];
    den_m[tid] = fmaxf(s, 1e-6f);
  }

  // ---- price mean over T: xs[r][0..157] ----
  if (tid < DD) {
    for (int r = 0; r < RPB; ++r) {
      const float* pr = price + ((size_t)(row0 + r) * TT) * DD + tid;
      float acc = 0.f;
      #pragma unroll
      for (int t = 0; t < TT; ++t) acc += pr[(size_t)t * DD];
      xs[r][tid] = acc * (1.0f / (float)TT);   // /32 exact (pow2)
    }
  }
  __syncthreads();

  // ---- news masked mean: xs[r][158..1181], float4-coalesced streaming ----
  {
    const int j0 = tid * 4;                      // 256 threads x 4 cols = 1024
    for (int r = 0; r < RPB; ++r) {
      const float* nb = news + ((size_t)(row0 + r) * TT) * NEWSC + j0;
      const float* mb = mask + (size_t)(row0 + r) * TT;
      float ax = 0.f, ay = 0.f, az = 0.f, aw = 0.f;
      #pragma unroll 4
      for (int t = 0; t < TT; ++t) {
        const float  mv = mb[t];                 // uniform -> scalar load
        const float4 nv = *(const float4*)(nb + (size_t)t * NEWSC);
        ax += mv * nv.x; ay += mv * nv.y; az += mv * nv.z; aw += mv * nv.w;
      }
      const float dn = den_m[r];
      xs[r][DD + j0 + 0] = ax / dn;
      xs[r][DD + j0 + 1] = ay / dn;
      xs[r][DD + j0 + 2] = az / dn;
      xs[r][DD + j0 + 3] = aw / dn;
    }
  }
  __syncthreads();

  // ---- router GEMM: h[r][o] = tanh(sum_i x[r][i]*rW[i][o] + rb[o]) ----
  {
    const int sh = tid >> 7;                     // i-range half
    const int o  = tid & 127;
    const int ib = sh ? SPLIT : 0;
    const int ie = sh ? XDIM : SPLIT;
    float acc[RPB];
    #pragma unroll
    for (int r = 0; r < RPB; ++r) acc[r] = 0.f;
    int i0 = ib;
    for (; i0 + 8 <= ie; i0 += 8) {
      const float w0 = rW[(size_t)(i0 + 0) * DGRU + o];
      const float w1 = rW[(size_t)(i0 + 1) * DGRU + o];
      const float w2 = rW[(size_t)(i0 + 2) * DGRU + o];
      const float w3 = rW[(size_t)(i0 + 3) * DGRU + o];
      const float w4 = rW[(size_t)(i0 + 4) * DGRU + o];
      const float w5 = rW[(size_t)(i0 + 5) * DGRU + o];
      const float w6 = rW[(size_t)(i0 + 6) * DGRU + o];
      const float w7 = rW[(size_t)(i0 + 7) * DGRU + o];
      #pragma unroll
      for (int r = 0; r < RPB; ++r) {            // broadcast b128 LDS reads (free)
        const float4 xa = *(const float4*)&xs[r][i0];
        const float4 xb = *(const float4*)&xs[r][i0 + 4];
        acc[r] += xa.x * w0 + xa.y * w1 + xa.z * w2 + xa.w * w3
                + xb.x * w4 + xb.y * w5 + xb.z * w6 + xb.w * w7;
      }
    }
    for (; i0 < ie; ++i0) {                      // ragged tail (6 iters, sh==1 only)
      const float w = rW[(size_t)i0 * DGRU + o];
      #pragma unroll
      for (int r = 0; r < RPB; ++r) acc[r] += xs[r][i0] * w;
    }
    if (sh) {
      #pragma unroll
      for (int r = 0; r < RPB; ++r) part[r][o] = acc[r];
    }
    __syncthreads();                             // xs dead from here on
    if (!sh) {
      const float b = rb[o];
      #pragma unroll
      for (int r = 0; r < RPB; ++r) hs[r][o] = tanhf(acc[r] + part[r][o] + b);
    }
    // stage expert_W transposed into the dead xs region: eWt[j*65+ge] = eW[ge*64+j]
    #pragma unroll
    for (int kk = 0; kk < 16; ++kk) {
      const int f  = tid + 256 * kk;
      const int ge = f >> 6;
      const int j  = f & 63;
      eWt[j * 65 + ge] = eW[f];
    }
  }
  __syncthreads();

  // ---- per-wave row ownership: wave wgi handles rows wgi and wgi+4 ----
  const int wgi = tid >> 6;
  const int ln  = tid & 63;
  const int ra  = wgi;
  const int rb2 = wgi + 4;

  // ---- hidden = h @ gate_W + gb ----
  float h0 = gb[ln], h1 = gb[ln];
  #pragma unroll 4
  for (int i = 0; i < DGRU; ++i) {
    const float w = gW[(size_t)i * HIDN + ln];   // coalesced, L1-resident
    h0 += hs[ra][i]  * w;
    h1 += hs[rb2][i] * w;
  }
  hid_s[ra][ln]  = h0;
  hid_s[rb2][ln] = h1;
  __syncthreads();

  float* out_pred = out;
  float* out_rw1  = out + (size_t)nrows;
  float* out_hid  = out + (size_t)nrows * 65;
  float* out_idx  = out + (size_t)nrows * 129;
  float* out_rw2  = out + (size_t)nrows * 131;

  // ---- top-2 + routing softmax + outputs (hidden, rw x2, indices) ----
  const float hvv[2] = {h0, h1};
  int   i1v[2], i2v[2];
  float w1v[2], w2v[2];
  #pragma unroll
  for (int rr = 0; rr < 2; ++rr) {
    const int r   = wgi + rr * 4;
    const int row = row0 + r;
    const float hv = hvv[rr];
    // 64-lane all-reduce argmax, lower-index tie-break (matches lax.top_k)
    float bv = hv; int bi = ln;
    #pragma unroll
    for (int off = 32; off >= 1; off >>= 1) {
      const float ov = __shfl_xor(bv, off);
      const int   oi = __shfl_xor(bi, off);
      if (ov > bv || (ov == bv && oi < bi)) { bv = ov; bi = oi; }
    }
    float cv = (ln == bi) ? -1e30f : hv; int ci = ln;
    #pragma unroll
    for (int off = 32; off >= 1; off >>= 1) {
      const float ov = __shfl_xor(cv, off);
      const int   oi = __shfl_xor(ci, off);
      if (ov > cv || (ov == cv && oi < ci)) { cv = ov; ci = oi; }
    }
    // softmax of masked hidden: exp(-1e30 - m1) underflows to 0 exactly
    const float e2 = expf(cv - bv);
    const float zi = 1.0f / (1.0f + e2);
    const float rwl = (ln == bi) ? zi : (ln == ci) ? e2 * zi : 0.0f;
    out_hid[(size_t)row * 64 + ln] = hv;
    out_rw1[(size_t)row * 64 + ln] = rwl;
    out_rw2[(size_t)row * 64 + ln] = rwl;
    if (ln < 2) out_idx[(size_t)row * 2 + ln] = (float)(ln == 0 ? bi : ci);
    i1v[rr] = bi; i2v[rr] = ci; w1v[rr] = zi; w2v[rr] = e2 * zi;
  }

  // ---- expert_out[ge] = sum_j hidden[j] * eW[ge][j] + eb[ge] ----
  {
    float a0 = eb[ln], a1 = eb[ln];
    #pragma unroll 4
    for (int j = 0; j < HIDN; ++j) {
      const float w = eWt[j * 65 + ln];          // stride-65: conflict-free
      a0 += hid_s[ra][j]  * w;
      a1 += hid_s[rb2][j] * w;
    }
    eo_s[ra][ln]  = a0;
    eo_s[rb2][ln] = a1;
  }
  __syncthreads();

  // ---- q/k/v: [g][f] = sum_e eo[g][e] * w[g][f][e] + b[g][f] ----
  const int gg = ln >> 3;
  #pragma unroll
  for (int rr = 0; rr < 2; ++rr) {
    const int r = wgi + rr * 4;
    float aq = wqb[ln], ak = wkb[ln], av = wvb[ln];
    #pragma unroll
    for (int ee = 0; ee < 8; ++ee) {
      const float xv = eo_s[r][gg * 8 + ee];
      aq += xv * wq[ln * 8 + ee];                // wq[(g*8+f)*8+e] = wq[ln*8+ee]
      ak += xv * wk[ln * 8 + ee];
      av += xv * wv[ln * 8 + ee];
    }
    q_s[r][ln] = aq; k_s[r][ln] = ak; v_s[r][ln] = av;
  }
  __syncthreads();

  // ---- tiny attention: per lane (g, e_out) with e_out = hh*2 + d ----
  {
    const int e8  = ln & 7;
    const int dd2 = e8 & 1;
    const int hh  = e8 >> 1;
    const float rs2 = 0.7071067811865476f;       // 1/sqrt(DH)
    #pragma unroll
    for (int rr = 0; rr < 2; ++rr) {
      const int r = wgi + rr * 4;
      float s0 = 0.f, s1 = 0.f;
      #pragma unroll
      for (int h2 = 0; h2 < 4; ++h2) {           // scores[d][e2] over H
        const float qv = q_s[r][gg * 8 + h2 * 2 + dd2];
        s0 += qv * k_s[r][gg * 8 + h2 * 2 + 0];
        s1 += qv * k_s[r][gg * 8 + h2 * 2 + 1];
      }
      s0 *= rs2; s1 *= rs2;
      const float mx = fmaxf(s0, s1);
      const float a0 = expf(s0 - mx);
      const float a1 = expf(s1 - mx);
      const float zi = 1.0f / (a0 + a1);
      att_s[r][ln] = (a0 * v_s[r][gg * 8 + hh * 2 + 0]
                    + a1 * v_s[r][gg * 8 + hh * 2 + 1]) * zi;
    }
  }
  __syncthreads();

  // ---- agg = att @ wo^T + wo_b; predictions = sum(agg * routing) ----
  #pragma unroll
  for (int rr = 0; rr < 2; ++rr) {
    const int r   = wgi + rr * 4;
    const int row = row0 + r;
    float acc = wob[ln];
    #pragma unroll
    for (int ee = 0; ee < 8; ++ee)
      acc += att_s[r][gg * 8 + ee] * wo[ln * 8 + ee];
    const float rwl = (ln == i1v[rr]) ? w1v[rr] : (ln == i2v[rr]) ? w2v[rr] : 0.0f;
    float ps = acc * rwl;
    #pragma unroll
    for (int off = 32; off >= 1; off >>= 1) ps += __shfl_xor(ps, off);
    if (ln == 0) out_pred[row] = ps;
  }
}

} // namespace

extern "C" void kernel_launch(void* const* d_in, const int* in_sizes, int n_in,
                              void* d_out, int out_size, void* d_ws, size_t ws_size,
                              hipStream_t stream) {
  const float* price = (const float*)d_in[0];
  const float* news  = (const float*)d_in[1];
  const float* mask  = (const float*)d_in[2];
  const float* rW    = (const float*)d_in[3];
  const float* rb    = (const float*)d_in[4];
  const float* gW    = (const float*)d_in[5];
  const float* gb    = (const float*)d_in[6];
  const float* eW    = (const float*)d_in[7];
  const float* eb    = (const float*)d_in[8];
  const float* wq    = (const float*)d_in[9];
  const float* wqb   = (const float*)d_in[10];
  const float* wk    = (const float*)d_in[11];
  const float* wkb   = (const float*)d_in[12];
  const float* wv    = (const float*)d_in[13];
  const float* wvb   = (const float*)d_in[14];
  const float* wo    = (const float*)d_in[15];
  const float* wob   = (const float*)d_in[16];
  float* out = (float*)d_out;
  const int nrows = in_sizes[2] / TT;            // news_mask is (N, T)
  (void)d_ws; (void)ws_size; (void)out_size; (void)n_in;
  miga_fused<<<dim3(nrows / RPB), dim3(256), 0, stream>>>(
      price, news, mask, rW, rb, gW, gb, eW, eb,
      wq, wqb, wk, wkb, wv, wvb, wo, wob, out, nrows);
}